// Round 1
// baseline (880.969 us; speedup 1.0000x reference)
//
#include <hip/hip_runtime.h>
#include <hip/hip_bf16.h>
#include <stdint.h>

constexpr int N_NODES = 50000;
constexpr int N_EDGES = 1600000;
constexpr int IN_DIM  = 500;
constexpr int HID     = 64;
constexpr int KW      = 125;   // per-wave K chunk (4 waves * 125 = 500)
constexpr int OUTC    = 68;    // 64 h2 cols + 4 composed projection cols

#define DEVI __device__ __forceinline__

DEVI float wred64(float v) {
#pragma unroll
    for (int m = 32; m; m >>= 1) v += __shfl_xor(v, m, 64);
    return v;
}

// ---------------- CSR build ----------------
__global__ void k_count(const int* __restrict__ dst, int* __restrict__ cnt) {
    int e = blockIdx.x * 256 + threadIdx.x;
    if (e < N_EDGES) atomicAdd(&cnt[dst[e]], 1);
}

__global__ void k_block_sums(const int* __restrict__ cnt, int* __restrict__ bsum) {
    __shared__ int red[256];
    int t = threadIdx.x;
    int i0 = blockIdx.x * 512 + t;
    int a = (i0 < N_NODES) ? cnt[i0] : 0;
    int b = (i0 + 256 < N_NODES) ? cnt[i0 + 256] : 0;
    red[t] = a + b;
    __syncthreads();
    for (int s = 128; s > 0; s >>= 1) {
        if (t < s) red[t] += red[t + s];
        __syncthreads();
    }
    if (t == 0) bsum[blockIdx.x] = red[0];
}

__global__ void k_scan_mid(const int* __restrict__ bsum, int* __restrict__ ex,
                           int* __restrict__ rowptr, int nb) {
    __shared__ int lds[128];
    int t = threadIdx.x;
    int v = (t < nb) ? bsum[t] : 0;
    lds[t] = v;
    __syncthreads();
    for (int d = 1; d < 128; d <<= 1) {
        int w = (t >= d) ? lds[t - d] : 0;
        __syncthreads();
        lds[t] += w;
        __syncthreads();
    }
    if (t < nb) ex[t] = lds[t] - v;
    if (t == 127) rowptr[N_NODES] = lds[127];
}

__global__ void k_scan_final(const int* __restrict__ cnt, const int* __restrict__ ex,
                             int* __restrict__ rowptr, int* __restrict__ cursor,
                             float* __restrict__ dinv) {
    __shared__ int lds[256];
    int t = threadIdx.x;
    int i0 = blockIdx.x * 512 + 2 * t;
    int i1 = i0 + 1;
    int a0 = (i0 < N_NODES) ? cnt[i0] : 0;
    int a1 = (i1 < N_NODES) ? cnt[i1] : 0;
    int s = a0 + a1;
    lds[t] = s;
    __syncthreads();
    for (int d = 1; d < 256; d <<= 1) {
        int w = (t >= d) ? lds[t - d] : 0;
        __syncthreads();
        lds[t] += w;
        __syncthreads();
    }
    int base = ex[blockIdx.x] + lds[t] - s;  // exclusive offset of this pair
    if (i0 < N_NODES) {
        rowptr[i0] = base; cursor[i0] = base;
        dinv[i0] = rsqrtf((float)(a0 > 1 ? a0 : 1));
    }
    if (i1 < N_NODES) {
        rowptr[i1] = base + a0; cursor[i1] = base + a0;
        dinv[i1] = rsqrtf((float)(a1 > 1 ? a1 : 1));
    }
}

__global__ void k_scatter(const int* __restrict__ src, const int* __restrict__ dst,
                          int* __restrict__ cursor, int* __restrict__ csr_src) {
    int e = blockIdx.x * 256 + threadIdx.x;
    if (e < N_EDGES) {
        int v = dst[e];
        int pos = atomicAdd(&cursor[v], 1);
        csr_src[pos] = src[e];
    }
}

// ---------------- weight prep: Wp[500][68] = [W1 | Wl@glw_pd0 | Wl@glw_ps0 | Wl@glw_pd1 | Wl@glw_ps1] ----
__global__ void k_prep(const float* __restrict__ Wl, const float* __restrict__ bl,
                       const float* __restrict__ glw, const float* __restrict__ glb,
                       const float* __restrict__ W1,
                       float* __restrict__ Wp, float* __restrict__ consts) {
    int idx = blockIdx.x * 256 + threadIdx.x;
    if (idx < IN_DIM * OUTC) {
        int k = idx / OUTC, c = idx - k * OUTC;
        float v;
        if (c < HID) {
            v = W1[k * HID + c];
        } else {
            int pp = c - HID, g = pp >> 1, half = pp & 1;
            const float* wv = glw + g * 128 + half * 64;
            float s = 0.f;
            for (int j = 0; j < 64; ++j) s += Wl[k * 64 + j] * wv[j];
            v = s;
        }
        Wp[idx] = v;
    }
    if (idx < 4) {  // bias constants folded into projections
        int g = idx >> 1, half = idx & 1;
        const float* wv = glw + g * 128 + half * 64;
        float s = 0.f;
        for (int j = 0; j < 64; ++j) s += bl[j] * wv[j];
        if (half) s += glb[g];
        consts[idx] = s;
    }
}

// ---------------- fused front GEMM: h2 = relu(x@W1+b1), proj = x@(composed) + consts ----
__global__ __launch_bounds__(256)
void k_gemm_front(const float* __restrict__ x, const float* __restrict__ Wp,
                  const float* __restrict__ consts, const float* __restrict__ b1,
                  float* __restrict__ h2, float* __restrict__ proj) {
    __shared__ float lds[64 * 69];  // stride 69: conflict-free (69 mod 32 = 5, odd)
    int tid = threadIdx.x;
    int wave = __builtin_amdgcn_readfirstlane(tid >> 6);
    int lane = tid & 63;
    int row = blockIdx.x * 64 + lane;
    bool valid = row < N_NODES;
    const float* xrow = x + (size_t)row * IN_DIM;

    float4 acc[17];
#pragma unroll
    for (int i = 0; i < 17; ++i) acc[i] = make_float4(0.f, 0.f, 0.f, 0.f);

    int k0 = wave * KW;
    for (int k = k0; k < k0 + KW; ++k) {
        float xv = valid ? xrow[k] : 0.f;
        const float4* Wk = (const float4*)(Wp + k * OUTC);  // 68 floats = 17 float4, 16B aligned
#pragma unroll
        for (int i = 0; i < 17; ++i) {
            float4 w = Wk[i];
            acc[i].x = fmaf(xv, w.x, acc[i].x);
            acc[i].y = fmaf(xv, w.y, acc[i].y);
            acc[i].z = fmaf(xv, w.z, acc[i].z);
            acc[i].w = fmaf(xv, w.w, acc[i].w);
        }
    }
    for (int i = tid; i < 64 * 69; i += 256) lds[i] = 0.f;
    __syncthreads();
    float* myrow = lds + lane * 69;
#pragma unroll
    for (int i = 0; i < 17; ++i) {
        atomicAdd(&myrow[4 * i + 0], acc[i].x);
        atomicAdd(&myrow[4 * i + 1], acc[i].y);
        atomicAdd(&myrow[4 * i + 2], acc[i].z);
        atomicAdd(&myrow[4 * i + 3], acc[i].w);
    }
    __syncthreads();
    int rbase = blockIdx.x * 64;
    for (int i = tid; i < 64 * 64; i += 256) {
        int r = i >> 6, c = i & 63;
        int rr = rbase + r;
        if (rr < N_NODES) h2[(size_t)rr * 64 + c] = fmaxf(lds[r * 69 + c] + b1[c], 0.f);
    }
    for (int i = tid; i < 64 * 4; i += 256) {
        int r = i >> 2, pp = i & 3;
        int rr = rbase + r;
        if (rr < N_NODES) proj[rr * 4 + pp] = lds[r * 69 + 64 + pp] + consts[pp];
    }
}

// ---------------- hop 0 (both graphs fused), feat=h2; also hop-1 gate projections ----
__global__ __launch_bounds__(256)
void k_hop0(const int* __restrict__ rowptr, const int* __restrict__ csr_src,
            const float* __restrict__ dinv, const float* __restrict__ proj,
            const float* __restrict__ h2, const float* __restrict__ faw,
            const float* __restrict__ fab,
            float* __restrict__ featcat, float* __restrict__ p1) {
    int wave = __builtin_amdgcn_readfirstlane(threadIdx.x >> 6);
    int lane = threadIdx.x & 63;
    int v = blockIdx.x * 4 + wave;
    int s = __builtin_amdgcn_readfirstlane(rowptr[v]);
    int e = __builtin_amdgcn_readfirstlane(rowptr[v + 1]);
    float dv = dinv[v];
    float pd0 = proj[v * 4 + 0];
    float pd1 = proj[v * 4 + 2];
    float acc0 = 0.f, acc1 = 0.f;
    for (int pos = s; pos < e; ++pos) {
        int u = __builtin_amdgcn_readfirstlane(csr_src[pos]);
        float du = dinv[u];
        float ps0 = proj[u * 4 + 1];
        float ps1 = proj[u * 4 + 3];
        float dd = dv * du;
        float t0 = tanhf(pd0 + ps0) * dd;
        float t1 = tanhf(pd1 + ps1) * dd;
        float hval = h2[(size_t)u * 64 + lane];
        acc0 = fmaf(t0, hval, acc0);
        acc1 = fmaf(t1, hval, acc1);
    }
    float h2v = h2[(size_t)v * 64 + lane];
    float f0 = fmaf(0.7f, acc0, 0.3f * h2v);
    float f1 = fmaf(0.7f, acc1, 0.3f * h2v);
    featcat[(size_t)v * 128 + lane] = f0;
    featcat[(size_t)v * 128 + 64 + lane] = f1;
    // hop-1 gate projections: p1 = [pd0, ps0(+b), pd1, ps1(+b)]
    float wpd0 = faw[1 * 128 + lane];        // fa_w[0,1,:64]
    float wps0 = faw[1 * 128 + 64 + lane];   // fa_w[0,1,64:]
    float wpd1 = faw[3 * 128 + lane];        // fa_w[1,1,:64]
    float wps1 = faw[3 * 128 + 64 + lane];   // fa_w[1,1,64:]
    float r0 = wred64(f0 * wpd0);
    float r1 = wred64(f0 * wps0);
    float r2 = wred64(f1 * wpd1);
    float r3 = wred64(f1 * wps1);
    if (lane == 0) {
        p1[v * 4 + 0] = r0;
        p1[v * 4 + 1] = r1 + fab[1];   // fa_b[0,1]
        p1[v * 4 + 2] = r2;
        p1[v * 4 + 3] = r3 + fab[3];   // fa_b[1,1]
    }
}

// ---------------- hop 1 (both graphs fused) + final output GEMM [128]->7 ----
__global__ __launch_bounds__(256)
void k_hop1(const int* __restrict__ rowptr, const int* __restrict__ csr_src,
            const float* __restrict__ dinv, const float* __restrict__ p1,
            const float* __restrict__ featcat, const float* __restrict__ h2,
            const float* __restrict__ W2, const float* __restrict__ b2,
            float* __restrict__ out) {
    int wave = __builtin_amdgcn_readfirstlane(threadIdx.x >> 6);
    int lane = threadIdx.x & 63;
    int v = blockIdx.x * 4 + wave;
    int s = __builtin_amdgcn_readfirstlane(rowptr[v]);
    int e = __builtin_amdgcn_readfirstlane(rowptr[v + 1]);
    float dv = dinv[v];
    float pd0 = p1[v * 4 + 0];
    float pd1 = p1[v * 4 + 2];
    float acc0 = 0.f, acc1 = 0.f;
    for (int pos = s; pos < e; ++pos) {
        int u = __builtin_amdgcn_readfirstlane(csr_src[pos]);
        float du = dinv[u];
        float ps0 = p1[u * 4 + 1];
        float ps1 = p1[u * 4 + 3];
        float dd = dv * du;
        float t0 = tanhf(pd0 + ps0) * dd;
        float t1 = tanhf(pd1 + ps1) * dd;
        float g0 = featcat[(size_t)u * 128 + lane];
        float g1 = featcat[(size_t)u * 128 + 64 + lane];
        acc0 = fmaf(t0, g0, acc0);
        acc1 = fmaf(t1, g1, acc1);
    }
    float h2v = h2[(size_t)v * 64 + lane];
    float f0 = fmaf(0.7f, acc0, 0.3f * h2v);
    float f1 = fmaf(0.7f, acc1, 0.3f * h2v);
#pragma unroll
    for (int o = 0; o < 7; ++o) {
        float contrib = f0 * W2[lane * 7 + o] + f1 * W2[(64 + lane) * 7 + o];
        float sum = wred64(contrib);
        if (lane == 0) out[v * 7 + o] = sum + b2[o];
    }
}

extern "C" void kernel_launch(void* const* d_in, const int* in_sizes, int n_in,
                              void* d_out, int out_size, void* d_ws, size_t ws_size,
                              hipStream_t stream) {
    const float* x   = (const float*)d_in[0];
    const int*   src = (const int*)d_in[1];
    const int*   dst = (const int*)d_in[2];
    const float* Wl  = (const float*)d_in[3];
    const float* bl  = (const float*)d_in[4];
    const float* glw = (const float*)d_in[5];
    const float* glb = (const float*)d_in[6];
    const float* W1  = (const float*)d_in[7];
    const float* b1  = (const float*)d_in[8];
    const float* faw = (const float*)d_in[9];
    const float* fab = (const float*)d_in[10];
    const float* W2  = (const float*)d_in[11];
    const float* b2  = (const float*)d_in[12];
    float* out = (float*)d_out;

    uint8_t* p = (uint8_t*)d_ws;
    auto carve = [&](size_t bytes) {
        uint8_t* q = p;
        p += (bytes + 255) & ~(size_t)255;
        return q;
    };
    float* Wp      = (float*)carve(IN_DIM * OUTC * 4);
    float* consts  = (float*)carve(16);
    int*   cnt     = (int*)carve(N_NODES * 4);
    int*   rowptr  = (int*)carve((N_NODES + 1) * 4);
    int*   cursor  = (int*)carve(N_NODES * 4);
    float* dinv    = (float*)carve(N_NODES * 4);
    int*   bsum    = (int*)carve(98 * 4);
    int*   ex      = (int*)carve(98 * 4);
    int*   csr_src = (int*)carve(N_EDGES * 4);
    float* h2      = (float*)carve((size_t)N_NODES * 64 * 4);
    float* proj    = (float*)carve(N_NODES * 4 * 4);
    float* featcat = (float*)carve((size_t)N_NODES * 128 * 4);
    float* p1b     = (float*)carve(N_NODES * 4 * 4);

    hipMemsetAsync(cnt, 0, N_NODES * 4, stream);
    k_count<<<(N_EDGES + 255) / 256, 256, 0, stream>>>(dst, cnt);
    k_block_sums<<<98, 256, 0, stream>>>(cnt, bsum);
    k_scan_mid<<<1, 128, 0, stream>>>(bsum, ex, rowptr, 98);
    k_scan_final<<<98, 256, 0, stream>>>(cnt, ex, rowptr, cursor, dinv);
    k_scatter<<<(N_EDGES + 255) / 256, 256, 0, stream>>>(src, dst, cursor, csr_src);
    k_prep<<<(IN_DIM * OUTC + 255) / 256, 256, 0, stream>>>(Wl, bl, glw, glb, W1, Wp, consts);
    k_gemm_front<<<(N_NODES + 63) / 64, 256, 0, stream>>>(x, Wp, consts, b1, h2, proj);
    k_hop0<<<N_NODES / 4, 256, 0, stream>>>(rowptr, csr_src, dinv, proj, h2, faw, fab, featcat, p1b);
    k_hop1<<<N_NODES / 4, 256, 0, stream>>>(rowptr, csr_src, dinv, p1b, featcat, h2, W2, b2, out);
}

// Round 2
// 760.776 us; speedup vs baseline: 1.1580x; 1.1580x over previous
//
#include <hip/hip_runtime.h>
#include <hip/hip_bf16.h>
#include <stdint.h>

constexpr int N_NODES = 50000;
constexpr int N_EDGES = 1600000;
constexpr int IN_DIM  = 500;
constexpr int KPAD    = 512;   // zero-padded K for clean 16x32 tiling
constexpr int HID     = 64;
constexpr int OUTC    = 68;    // 64 h2 cols + 4 composed projection cols

#define DEVI __device__ __forceinline__

DEVI float wred64(float v) {
#pragma unroll
    for (int m = 32; m; m >>= 1) v += __shfl_xor(v, m, 64);
    return v;
}

// ---------------- CSR build ----------------
__global__ void k_count(const int* __restrict__ dst, int* __restrict__ cnt) {
    int e = blockIdx.x * 256 + threadIdx.x;
    if (e < N_EDGES) atomicAdd(&cnt[dst[e]], 1);
}

__global__ void k_block_sums(const int* __restrict__ cnt, int* __restrict__ bsum) {
    __shared__ int red[256];
    int t = threadIdx.x;
    int i0 = blockIdx.x * 512 + t;
    int a = (i0 < N_NODES) ? cnt[i0] : 0;
    int b = (i0 + 256 < N_NODES) ? cnt[i0 + 256] : 0;
    red[t] = a + b;
    __syncthreads();
    for (int s = 128; s > 0; s >>= 1) {
        if (t < s) red[t] += red[t + s];
        __syncthreads();
    }
    if (t == 0) bsum[blockIdx.x] = red[0];
}

__global__ void k_scan_mid(const int* __restrict__ bsum, int* __restrict__ ex,
                           int* __restrict__ rowptr, int nb) {
    __shared__ int lds[128];
    int t = threadIdx.x;
    int v = (t < nb) ? bsum[t] : 0;
    lds[t] = v;
    __syncthreads();
    for (int d = 1; d < 128; d <<= 1) {
        int w = (t >= d) ? lds[t - d] : 0;
        __syncthreads();
        lds[t] += w;
        __syncthreads();
    }
    if (t < nb) ex[t] = lds[t] - v;
    if (t == 127) rowptr[N_NODES] = lds[127];
}

__global__ void k_scan_final(const int* __restrict__ cnt, const int* __restrict__ ex,
                             int* __restrict__ rowptr, int* __restrict__ cursor,
                             float* __restrict__ dinv) {
    __shared__ int lds[256];
    int t = threadIdx.x;
    int i0 = blockIdx.x * 512 + 2 * t;
    int i1 = i0 + 1;
    int a0 = (i0 < N_NODES) ? cnt[i0] : 0;
    int a1 = (i1 < N_NODES) ? cnt[i1] : 0;
    int s = a0 + a1;
    lds[t] = s;
    __syncthreads();
    for (int d = 1; d < 256; d <<= 1) {
        int w = (t >= d) ? lds[t - d] : 0;
        __syncthreads();
        lds[t] += w;
        __syncthreads();
    }
    int base = ex[blockIdx.x] + lds[t] - s;  // exclusive offset of this pair
    if (i0 < N_NODES) {
        rowptr[i0] = base; cursor[i0] = base;
        dinv[i0] = rsqrtf((float)(a0 > 1 ? a0 : 1));
    }
    if (i1 < N_NODES) {
        rowptr[i1] = base + a0; cursor[i1] = base + a0;
        dinv[i1] = rsqrtf((float)(a1 > 1 ? a1 : 1));
    }
}

__global__ void k_scatter(const int* __restrict__ src, const int* __restrict__ dst,
                          int* __restrict__ cursor, int* __restrict__ csr_src) {
    int e = blockIdx.x * 256 + threadIdx.x;
    if (e < N_EDGES) {
        int v = dst[e];
        int pos = atomicAdd(&cursor[v], 1);
        csr_src[pos] = src[e];
    }
}

// ---- weight prep: Wp[512][68] = [W1 | Wl@glw_pd0 | Wl@glw_ps0 | Wl@glw_pd1 | Wl@glw_ps1], 0 for k>=500 ----
__global__ void k_prep(const float* __restrict__ Wl, const float* __restrict__ bl,
                       const float* __restrict__ glw, const float* __restrict__ glb,
                       const float* __restrict__ W1,
                       float* __restrict__ Wp, float* __restrict__ consts) {
    int idx = blockIdx.x * 256 + threadIdx.x;
    if (idx < KPAD * OUTC) {
        int k = idx / OUTC, c = idx - k * OUTC;
        float v = 0.f;
        if (k < IN_DIM) {
            if (c < HID) {
                v = W1[k * HID + c];
            } else {
                int pp = c - HID, g = pp >> 1, half = pp & 1;
                const float* wv = glw + g * 128 + half * 64;
                float s = 0.f;
                for (int j = 0; j < 64; ++j) s += Wl[k * 64 + j] * wv[j];
                v = s;
            }
        }
        Wp[idx] = v;
    }
    if (idx < 4) {  // bias constants folded into projections
        int g = idx >> 1, half = idx & 1;
        const float* wv = glw + g * 128 + half * 64;
        float s = 0.f;
        for (int j = 0; j < 64; ++j) s += bl[j] * wv[j];
        if (half) s += glb[g];
        consts[idx] = s;
    }
}

// ---------------- fused front GEMM: h2 = relu(x@W1+b1), proj = x@(composed) + consts ----
// BM=128 rows/block, BK=32, 256 threads. Thread tile = 2 rows x 17 cols.
// x staged transposed in LDS (coalesced global loads); weights via wave-uniform
// scalar loads (constant cache, no DS traffic).
__global__ __launch_bounds__(256)
void k_gemm_front(const float* __restrict__ x, const float* __restrict__ Wp,
                  const float* __restrict__ consts, const float* __restrict__ b1,
                  float* __restrict__ h2, float* __restrict__ proj) {
    __shared__ float xT[32][130];   // [k][row], stride 130 (even: aligned float2; 2-way banks on write)
    int tid  = threadIdx.x;
    int cg   = __builtin_amdgcn_readfirstlane(tid >> 6);  // wave-uniform col group 0..3
    int rg   = tid & 63;                                  // row pair 0..63
    int c0   = cg * 17;
    int rbase = blockIdx.x * 128;

    float acc[2][17];
#pragma unroll
    for (int r = 0; r < 2; ++r)
#pragma unroll
        for (int i = 0; i < 17; ++i) acc[r][i] = 0.f;

    int srow4 = tid >> 3;          // 0..31 (row within stage slice)
    int sk4   = (tid & 7) * 4;     // k offset 0,4,...,28

    for (int kt = 0; kt < 16; ++kt) {
        int k0 = kt * 32;
        // ---- stage x[rbase .. rbase+127][k0 .. k0+31] transposed into LDS ----
#pragma unroll
        for (int it = 0; it < 4; ++it) {
            int row  = srow4 + it * 32;          // 0..127
            int grow = rbase + row;
            int gk   = k0 + sk4;
            float4 v = make_float4(0.f, 0.f, 0.f, 0.f);
            if (grow < N_NODES) {
                if (gk + 3 < IN_DIM) {
                    v = *(const float4*)(x + (size_t)grow * IN_DIM + gk);
                } else {
                    const float* xr = x + (size_t)grow * IN_DIM;
                    if (gk + 0 < IN_DIM) v.x = xr[gk + 0];
                    if (gk + 1 < IN_DIM) v.y = xr[gk + 1];
                    if (gk + 2 < IN_DIM) v.z = xr[gk + 2];
                    if (gk + 3 < IN_DIM) v.w = xr[gk + 3];
                }
            }
            xT[sk4 + 0][row] = v.x;
            xT[sk4 + 1][row] = v.y;
            xT[sk4 + 2][row] = v.z;
            xT[sk4 + 3][row] = v.w;
        }
        __syncthreads();

        // ---- compute ----
        const float* wbase = Wp + k0 * OUTC + c0;
#pragma unroll 4
        for (int k = 0; k < 32; ++k) {
            float2 xv = *(const float2*)&xT[k][2 * rg];
            const float* wk = wbase + k * OUTC;  // wave-uniform -> s_load
            float w[17];
#pragma unroll
            for (int i = 0; i < 17; ++i) w[i] = wk[i];
#pragma unroll
            for (int i = 0; i < 17; ++i) {
                acc[0][i] = fmaf(xv.x, w[i], acc[0][i]);
                acc[1][i] = fmaf(xv.y, w[i], acc[1][i]);
            }
        }
        __syncthreads();
    }

    // ---- epilogue ----
#pragma unroll
    for (int r = 0; r < 2; ++r) {
        int grow = rbase + 2 * rg + r;
        if (grow >= N_NODES) continue;
#pragma unroll
        for (int i = 0; i < 17; ++i) {
            int c = c0 + i;
            float v = acc[r][i];
            if (c < HID) {
                h2[(size_t)grow * HID + c] = fmaxf(v + b1[c], 0.f);
            } else {
                proj[grow * 4 + (c - HID)] = v + consts[c - HID];
            }
        }
    }
}

// ---------------- hop 0 (both graphs fused), feat=h2; also hop-1 gate projections ----
__global__ __launch_bounds__(256)
void k_hop0(const int* __restrict__ rowptr, const int* __restrict__ csr_src,
            const float* __restrict__ dinv, const float* __restrict__ proj,
            const float* __restrict__ h2, const float* __restrict__ faw,
            const float* __restrict__ fab,
            float* __restrict__ featcat, float* __restrict__ p1) {
    int wave = __builtin_amdgcn_readfirstlane(threadIdx.x >> 6);
    int lane = threadIdx.x & 63;
    int v = blockIdx.x * 4 + wave;
    int s = __builtin_amdgcn_readfirstlane(rowptr[v]);
    int e = __builtin_amdgcn_readfirstlane(rowptr[v + 1]);
    float dv = dinv[v];
    float pd0 = proj[v * 4 + 0];
    float pd1 = proj[v * 4 + 2];
    float acc0 = 0.f, acc1 = 0.f;
    for (int pos = s; pos < e; ++pos) {
        int u = __builtin_amdgcn_readfirstlane(csr_src[pos]);
        float du = dinv[u];
        float ps0 = proj[u * 4 + 1];
        float ps1 = proj[u * 4 + 3];
        float dd = dv * du;
        float t0 = tanhf(pd0 + ps0) * dd;
        float t1 = tanhf(pd1 + ps1) * dd;
        float hval = h2[(size_t)u * 64 + lane];
        acc0 = fmaf(t0, hval, acc0);
        acc1 = fmaf(t1, hval, acc1);
    }
    float h2v = h2[(size_t)v * 64 + lane];
    float f0 = fmaf(0.7f, acc0, 0.3f * h2v);
    float f1 = fmaf(0.7f, acc1, 0.3f * h2v);
    featcat[(size_t)v * 128 + lane] = f0;
    featcat[(size_t)v * 128 + 64 + lane] = f1;
    // hop-1 gate projections: p1 = [pd0, ps0(+b), pd1, ps1(+b)]
    float wpd0 = faw[1 * 128 + lane];        // fa_w[0,1,:64]
    float wps0 = faw[1 * 128 + 64 + lane];   // fa_w[0,1,64:]
    float wpd1 = faw[3 * 128 + lane];        // fa_w[1,1,:64]
    float wps1 = faw[3 * 128 + 64 + lane];   // fa_w[1,1,64:]
    float r0 = wred64(f0 * wpd0);
    float r1 = wred64(f0 * wps0);
    float r2 = wred64(f1 * wpd1);
    float r3 = wred64(f1 * wps1);
    if (lane == 0) {
        p1[v * 4 + 0] = r0;
        p1[v * 4 + 1] = r1 + fab[1];   // fa_b[0,1]
        p1[v * 4 + 2] = r2;
        p1[v * 4 + 3] = r3 + fab[3];   // fa_b[1,1]
    }
}

// ---------------- hop 1 (both graphs fused) + final output GEMM [128]->7 ----
__global__ __launch_bounds__(256)
void k_hop1(const int* __restrict__ rowptr, const int* __restrict__ csr_src,
            const float* __restrict__ dinv, const float* __restrict__ p1,
            const float* __restrict__ featcat, const float* __restrict__ h2,
            const float* __restrict__ W2, const float* __restrict__ b2,
            float* __restrict__ out) {
    int wave = __builtin_amdgcn_readfirstlane(threadIdx.x >> 6);
    int lane = threadIdx.x & 63;
    int v = blockIdx.x * 4 + wave;
    int s = __builtin_amdgcn_readfirstlane(rowptr[v]);
    int e = __builtin_amdgcn_readfirstlane(rowptr[v + 1]);
    float dv = dinv[v];
    float pd0 = p1[v * 4 + 0];
    float pd1 = p1[v * 4 + 2];
    float acc0 = 0.f, acc1 = 0.f;
    for (int pos = s; pos < e; ++pos) {
        int u = __builtin_amdgcn_readfirstlane(csr_src[pos]);
        float du = dinv[u];
        float ps0 = p1[u * 4 + 1];
        float ps1 = p1[u * 4 + 3];
        float dd = dv * du;
        float t0 = tanhf(pd0 + ps0) * dd;
        float t1 = tanhf(pd1 + ps1) * dd;
        float g0 = featcat[(size_t)u * 128 + lane];
        float g1 = featcat[(size_t)u * 128 + 64 + lane];
        acc0 = fmaf(t0, g0, acc0);
        acc1 = fmaf(t1, g1, acc1);
    }
    float h2v = h2[(size_t)v * 64 + lane];
    float f0 = fmaf(0.7f, acc0, 0.3f * h2v);
    float f1 = fmaf(0.7f, acc1, 0.3f * h2v);
#pragma unroll
    for (int o = 0; o < 7; ++o) {
        float contrib = f0 * W2[lane * 7 + o] + f1 * W2[(64 + lane) * 7 + o];
        float sum = wred64(contrib);
        if (lane == 0) out[v * 7 + o] = sum + b2[o];
    }
}

extern "C" void kernel_launch(void* const* d_in, const int* in_sizes, int n_in,
                              void* d_out, int out_size, void* d_ws, size_t ws_size,
                              hipStream_t stream) {
    const float* x   = (const float*)d_in[0];
    const int*   src = (const int*)d_in[1];
    const int*   dst = (const int*)d_in[2];
    const float* Wl  = (const float*)d_in[3];
    const float* bl  = (const float*)d_in[4];
    const float* glw = (const float*)d_in[5];
    const float* glb = (const float*)d_in[6];
    const float* W1  = (const float*)d_in[7];
    const float* b1  = (const float*)d_in[8];
    const float* faw = (const float*)d_in[9];
    const float* fab = (const float*)d_in[10];
    const float* W2  = (const float*)d_in[11];
    const float* b2  = (const float*)d_in[12];
    float* out = (float*)d_out;

    uint8_t* p = (uint8_t*)d_ws;
    auto carve = [&](size_t bytes) {
        uint8_t* q = p;
        p += (bytes + 255) & ~(size_t)255;
        return q;
    };
    float* Wp      = (float*)carve((size_t)KPAD * OUTC * 4);
    float* consts  = (float*)carve(16);
    int*   cnt     = (int*)carve(N_NODES * 4);
    int*   rowptr  = (int*)carve((N_NODES + 1) * 4);
    int*   cursor  = (int*)carve(N_NODES * 4);
    float* dinv    = (float*)carve(N_NODES * 4);
    int*   bsum    = (int*)carve(98 * 4);
    int*   ex      = (int*)carve(98 * 4);
    int*   csr_src = (int*)carve(N_EDGES * 4);
    float* h2      = (float*)carve((size_t)N_NODES * 64 * 4);
    float* proj    = (float*)carve(N_NODES * 4 * 4);
    float* featcat = (float*)carve((size_t)N_NODES * 128 * 4);
    float* p1b     = (float*)carve(N_NODES * 4 * 4);

    hipMemsetAsync(cnt, 0, N_NODES * 4, stream);
    k_count<<<(N_EDGES + 255) / 256, 256, 0, stream>>>(dst, cnt);
    k_block_sums<<<98, 256, 0, stream>>>(cnt, bsum);
    k_scan_mid<<<1, 128, 0, stream>>>(bsum, ex, rowptr, 98);
    k_scan_final<<<98, 256, 0, stream>>>(cnt, ex, rowptr, cursor, dinv);
    k_scatter<<<(N_EDGES + 255) / 256, 256, 0, stream>>>(src, dst, cursor, csr_src);
    k_prep<<<(KPAD * OUTC + 255) / 256, 256, 0, stream>>>(Wl, bl, glw, glb, W1, Wp, consts);
    k_gemm_front<<<(N_NODES + 127) / 128, 256, 0, stream>>>(x, Wp, consts, b1, h2, proj);
    k_hop0<<<N_NODES / 4, 256, 0, stream>>>(rowptr, csr_src, dinv, proj, h2, faw, fab, featcat, p1b);
    k_hop1<<<N_NODES / 4, 256, 0, stream>>>(rowptr, csr_src, dinv, p1b, featcat, h2, W2, b2, out);
}

// Round 3
// 551.383 us; speedup vs baseline: 1.5977x; 1.3798x over previous
//
#include <hip/hip_runtime.h>
#include <hip/hip_bf16.h>
#include <stdint.h>

constexpr int N_NODES = 50000;
constexpr int N_EDGES = 1600000;
constexpr int IN_DIM  = 500;
constexpr int KPAD    = 512;   // zero-padded K for clean 16x32 tiling
constexpr int HID     = 64;
constexpr int OUTC    = 68;    // 64 h2 cols + 4 composed projection cols

#define DEVI __device__ __forceinline__

DEVI float wred64(float v) {
#pragma unroll
    for (int m = 32; m; m >>= 1) v += __shfl_xor(v, m, 64);
    return v;
}

DEVI float bf_hi(uint32_t u) { return __uint_as_float(u & 0xffff0000u); }
DEVI float bf_lo(uint32_t u) { return __uint_as_float(u << 16); }

DEVI uint16_t f2bf(float f) {
    union { __hip_bfloat16 h; uint16_t u; } c;
    c.h = __float2bfloat16(f);
    return c.u;
}

// ---------------- CSR build ----------------
__global__ void k_count(const int* __restrict__ dst, int* __restrict__ cnt) {
    int e = blockIdx.x * 256 + threadIdx.x;
    if (e < N_EDGES) atomicAdd(&cnt[dst[e]], 1);
}

__global__ void k_block_sums(const int* __restrict__ cnt, int* __restrict__ bsum) {
    __shared__ int red[256];
    int t = threadIdx.x;
    int i0 = blockIdx.x * 512 + t;
    int a = (i0 < N_NODES) ? cnt[i0] : 0;
    int b = (i0 + 256 < N_NODES) ? cnt[i0 + 256] : 0;
    red[t] = a + b;
    __syncthreads();
    for (int s = 128; s > 0; s >>= 1) {
        if (t < s) red[t] += red[t + s];
        __syncthreads();
    }
    if (t == 0) bsum[blockIdx.x] = red[0];
}

__global__ void k_scan_mid(const int* __restrict__ bsum, int* __restrict__ ex,
                           int* __restrict__ rowptr, int nb) {
    __shared__ int lds[128];
    int t = threadIdx.x;
    int v = (t < nb) ? bsum[t] : 0;
    lds[t] = v;
    __syncthreads();
    for (int d = 1; d < 128; d <<= 1) {
        int w = (t >= d) ? lds[t - d] : 0;
        __syncthreads();
        lds[t] += w;
        __syncthreads();
    }
    if (t < nb) ex[t] = lds[t] - v;
    if (t == 127) rowptr[N_NODES] = lds[127];
}

__global__ void k_scan_final(const int* __restrict__ cnt, const int* __restrict__ ex,
                             int* __restrict__ rowptr, int* __restrict__ cursor,
                             float* __restrict__ dinv) {
    __shared__ int lds[256];
    int t = threadIdx.x;
    int i0 = blockIdx.x * 512 + 2 * t;
    int i1 = i0 + 1;
    int a0 = (i0 < N_NODES) ? cnt[i0] : 0;
    int a1 = (i1 < N_NODES) ? cnt[i1] : 0;
    int s = a0 + a1;
    lds[t] = s;
    __syncthreads();
    for (int d = 1; d < 256; d <<= 1) {
        int w = (t >= d) ? lds[t - d] : 0;
        __syncthreads();
        lds[t] += w;
        __syncthreads();
    }
    int base = ex[blockIdx.x] + lds[t] - s;  // exclusive offset of this pair
    if (i0 < N_NODES) {
        rowptr[i0] = base; cursor[i0] = base;
        dinv[i0] = rsqrtf((float)(a0 > 1 ? a0 : 1));
    }
    if (i1 < N_NODES) {
        rowptr[i1] = base + a0; cursor[i1] = base + a0;
        dinv[i1] = rsqrtf((float)(a1 > 1 ? a1 : 1));
    }
}

// scatter + hop-0 edge factors (edge-parallel tanh; needs proj ready)
__global__ void k_scatter_fac(const int* __restrict__ src, const int* __restrict__ dst,
                              int* __restrict__ cursor, const float* __restrict__ dinv,
                              const float4* __restrict__ projv,
                              int* __restrict__ csr_src, int* __restrict__ csr_dst,
                              float2* __restrict__ fac0) {
    int e = blockIdx.x * 256 + threadIdx.x;
    if (e >= N_EDGES) return;
    int u = src[e], v = dst[e];
    int pos = atomicAdd(&cursor[v], 1);
    csr_src[pos] = u;
    csr_dst[pos] = v;
    float dd = dinv[v] * dinv[u];
    float4 pv = projv[v], pu = projv[u];
    fac0[pos] = make_float2(tanhf(pv.x + pu.y) * dd, tanhf(pv.z + pu.w) * dd);
}

// hop-1 edge factors from p1 (pos-parallel)
__global__ void k_fac1(const int* __restrict__ csr_src, const int* __restrict__ csr_dst,
                       const float* __restrict__ dinv, const float4* __restrict__ p1,
                       float2* __restrict__ fac1) {
    int pos = blockIdx.x * 256 + threadIdx.x;
    if (pos >= N_EDGES) return;
    int u = csr_src[pos], v = csr_dst[pos];
    float dd = dinv[v] * dinv[u];
    float4 pv = p1[v], pu = p1[u];
    fac1[pos] = make_float2(tanhf(pv.x + pu.y) * dd, tanhf(pv.z + pu.w) * dd);
}

// ---- weight prep: Wp[512][68] = [W1 | Wl@glw_pd0 | Wl@glw_ps0 | Wl@glw_pd1 | Wl@glw_ps1], 0 for k>=500 ----
__global__ void k_prep(const float* __restrict__ Wl, const float* __restrict__ bl,
                       const float* __restrict__ glw, const float* __restrict__ glb,
                       const float* __restrict__ W1,
                       float* __restrict__ Wp, float* __restrict__ consts) {
    int idx = blockIdx.x * 256 + threadIdx.x;
    if (idx < KPAD * OUTC) {
        int k = idx / OUTC, c = idx - k * OUTC;
        float v = 0.f;
        if (k < IN_DIM) {
            if (c < HID) {
                v = W1[k * HID + c];
            } else {
                int pp = c - HID, g = pp >> 1, half = pp & 1;
                const float* wv = glw + g * 128 + half * 64;
                float s = 0.f;
                for (int j = 0; j < 64; ++j) s += Wl[k * 64 + j] * wv[j];
                v = s;
            }
        }
        Wp[idx] = v;
    }
    if (idx < 4) {
        int g = idx >> 1, half = idx & 1;
        const float* wv = glw + g * 128 + half * 64;
        float s = 0.f;
        for (int j = 0; j < 64; ++j) s += bl[j] * wv[j];
        if (half) s += glb[g];
        consts[idx] = s;
    }
}

// ---------------- fused front GEMM: h2 = relu(x@W1+b1), proj = x@(composed) + consts ----
__global__ __launch_bounds__(256)
void k_gemm_front(const float* __restrict__ x, const float* __restrict__ Wp,
                  const float* __restrict__ consts, const float* __restrict__ b1,
                  float* __restrict__ h2f, uint16_t* __restrict__ h2b,
                  float* __restrict__ proj) {
    __shared__ float xT[32][130];
    int tid  = threadIdx.x;
    int cg   = __builtin_amdgcn_readfirstlane(tid >> 6);
    int rg   = tid & 63;
    int c0   = cg * 17;
    int rbase = blockIdx.x * 128;

    float acc[2][17];
#pragma unroll
    for (int r = 0; r < 2; ++r)
#pragma unroll
        for (int i = 0; i < 17; ++i) acc[r][i] = 0.f;

    int srow4 = tid >> 3;
    int sk4   = (tid & 7) * 4;

    for (int kt = 0; kt < 16; ++kt) {
        int k0 = kt * 32;
#pragma unroll
        for (int it = 0; it < 4; ++it) {
            int row  = srow4 + it * 32;
            int grow = rbase + row;
            int gk   = k0 + sk4;
            float4 v = make_float4(0.f, 0.f, 0.f, 0.f);
            if (grow < N_NODES) {
                if (gk + 3 < IN_DIM) {
                    v = *(const float4*)(x + (size_t)grow * IN_DIM + gk);
                } else {
                    const float* xr = x + (size_t)grow * IN_DIM;
                    if (gk + 0 < IN_DIM) v.x = xr[gk + 0];
                    if (gk + 1 < IN_DIM) v.y = xr[gk + 1];
                    if (gk + 2 < IN_DIM) v.z = xr[gk + 2];
                    if (gk + 3 < IN_DIM) v.w = xr[gk + 3];
                }
            }
            xT[sk4 + 0][row] = v.x;
            xT[sk4 + 1][row] = v.y;
            xT[sk4 + 2][row] = v.z;
            xT[sk4 + 3][row] = v.w;
        }
        __syncthreads();

        const float* wbase = Wp + k0 * OUTC + c0;
#pragma unroll 4
        for (int k = 0; k < 32; ++k) {
            float2 xv = *(const float2*)&xT[k][2 * rg];
            const float* wk = wbase + k * OUTC;
            float w[17];
#pragma unroll
            for (int i = 0; i < 17; ++i) w[i] = wk[i];
#pragma unroll
            for (int i = 0; i < 17; ++i) {
                acc[0][i] = fmaf(xv.x, w[i], acc[0][i]);
                acc[1][i] = fmaf(xv.y, w[i], acc[1][i]);
            }
        }
        __syncthreads();
    }

#pragma unroll
    for (int r = 0; r < 2; ++r) {
        int grow = rbase + 2 * rg + r;
        if (grow >= N_NODES) continue;
#pragma unroll
        for (int i = 0; i < 17; ++i) {
            int c = c0 + i;
            float v = acc[r][i];
            if (c < HID) {
                float hv = fmaxf(v + b1[c], 0.f);
                h2f[(size_t)grow * HID + c] = hv;
                h2b[(size_t)grow * HID + c] = f2bf(hv);
            } else {
                proj[grow * 4 + (c - HID)] = v + consts[c - HID];
            }
        }
    }
}

// ---------------- hop 0 (both graphs fused), feat=h2 (bf16 gather); writes interleaved bf16 featcat + p1 ----
__global__ __launch_bounds__(256)
void k_hop0(const int* __restrict__ rowptr, const int* __restrict__ csr_src,
            const float2* __restrict__ fac0, const uint16_t* __restrict__ h2b,
            const float* __restrict__ h2f, const float* __restrict__ faw,
            const float* __restrict__ fab,
            uint32_t* __restrict__ fc, float4* __restrict__ p1) {
    int wave = __builtin_amdgcn_readfirstlane(threadIdx.x >> 6);
    int lane = threadIdx.x & 63;
    int v = blockIdx.x * 4 + wave;
    int s = __builtin_amdgcn_readfirstlane(rowptr[v]);
    int e = __builtin_amdgcn_readfirstlane(rowptr[v + 1]);
    float acc0 = 0.f, acc1 = 0.f;
    for (int b2 = s; b2 < e; b2 += 64) {
        int pos = b2 + lane;
        bool val = pos < e;
        int idx = val ? csr_src[pos] : 0;
        float2 f = val ? fac0[pos] : make_float2(0.f, 0.f);
        int cnt = min(64, e - b2);
        for (int j = 0; j < cnt; ++j) {
            int u = __shfl(idx, j, 64);
            float t0 = __shfl(f.x, j, 64);
            float t1 = __shfl(f.y, j, 64);
            float hv = bf_lo((uint32_t)h2b[(size_t)u * 64 + lane]);
            acc0 = fmaf(t0, hv, acc0);
            acc1 = fmaf(t1, hv, acc1);
        }
    }
    float h2v = h2f[(size_t)v * 64 + lane];
    float f0 = fmaf(0.7f, acc0, 0.3f * h2v);
    float f1 = fmaf(0.7f, acc1, 0.3f * h2v);
    // interleaved bf16 featcat: lane writes (g0,g1) packed at col pair 2*lane
    fc[(size_t)v * 64 + lane] = (uint32_t)f2bf(f0) | ((uint32_t)f2bf(f1) << 16);
    // hop-1 gate projections
    float wpd0 = faw[1 * 128 + lane];
    float wps0 = faw[1 * 128 + 64 + lane];
    float wpd1 = faw[3 * 128 + lane];
    float wps1 = faw[3 * 128 + 64 + lane];
    float r0 = wred64(f0 * wpd0);
    float r1 = wred64(f0 * wps0);
    float r2 = wred64(f1 * wpd1);
    float r3 = wred64(f1 * wps1);
    if (lane == 0) p1[v] = make_float4(r0, r1 + fab[1], r2, r3 + fab[3]);
}

// ---------------- hop 1 (both graphs fused) + final output GEMM [128]->7 ----
__global__ __launch_bounds__(256)
void k_hop1(const int* __restrict__ rowptr, const int* __restrict__ csr_src,
            const float2* __restrict__ fac1, const uint32_t* __restrict__ fc,
            const float* __restrict__ h2f, const float* __restrict__ W2,
            const float* __restrict__ b2, float* __restrict__ out) {
    int wave = __builtin_amdgcn_readfirstlane(threadIdx.x >> 6);
    int lane = threadIdx.x & 63;
    int v = blockIdx.x * 4 + wave;
    int s = __builtin_amdgcn_readfirstlane(rowptr[v]);
    int e = __builtin_amdgcn_readfirstlane(rowptr[v + 1]);
    float acc0 = 0.f, acc1 = 0.f;
    for (int b2 = s; b2 < e; b2 += 64) {
        int pos = b2 + lane;
        bool val = pos < e;
        int idx = val ? csr_src[pos] : 0;
        float2 f = val ? fac1[pos] : make_float2(0.f, 0.f);
        int cnt = min(64, e - b2);
        for (int j = 0; j < cnt; ++j) {
            int u = __shfl(idx, j, 64);
            float t0 = __shfl(f.x, j, 64);
            float t1 = __shfl(f.y, j, 64);
            uint32_t pk = fc[(size_t)u * 64 + lane];
            acc0 = fmaf(t0, bf_lo(pk & 0xffffu), acc0);
            acc1 = fmaf(t1, bf_hi(pk), acc1);
        }
    }
    float h2v = h2f[(size_t)v * 64 + lane];
    float f0 = fmaf(0.7f, acc0, 0.3f * h2v);
    float f1 = fmaf(0.7f, acc1, 0.3f * h2v);
#pragma unroll
    for (int o = 0; o < 7; ++o) {
        float contrib = f0 * W2[lane * 7 + o] + f1 * W2[(64 + lane) * 7 + o];
        float sum = wred64(contrib);
        if (lane == 0) out[v * 7 + o] = sum + b2[o];
    }
}

extern "C" void kernel_launch(void* const* d_in, const int* in_sizes, int n_in,
                              void* d_out, int out_size, void* d_ws, size_t ws_size,
                              hipStream_t stream) {
    const float* x   = (const float*)d_in[0];
    const int*   src = (const int*)d_in[1];
    const int*   dst = (const int*)d_in[2];
    const float* Wl  = (const float*)d_in[3];
    const float* bl  = (const float*)d_in[4];
    const float* glw = (const float*)d_in[5];
    const float* glb = (const float*)d_in[6];
    const float* W1  = (const float*)d_in[7];
    const float* b1  = (const float*)d_in[8];
    const float* faw = (const float*)d_in[9];
    const float* fab = (const float*)d_in[10];
    const float* W2  = (const float*)d_in[11];
    const float* b2  = (const float*)d_in[12];
    float* out = (float*)d_out;

    uint8_t* p = (uint8_t*)d_ws;
    auto carve = [&](size_t bytes) {
        uint8_t* q = p;
        p += (bytes + 255) & ~(size_t)255;
        return q;
    };
    float*    Wp      = (float*)carve((size_t)KPAD * OUTC * 4);
    float*    consts  = (float*)carve(16);
    int*      cnt     = (int*)carve(N_NODES * 4);
    int*      rowptr  = (int*)carve((N_NODES + 1) * 4);
    int*      cursor  = (int*)carve(N_NODES * 4);
    float*    dinv    = (float*)carve(N_NODES * 4);
    int*      bsum    = (int*)carve(98 * 4);
    int*      ex      = (int*)carve(98 * 4);
    int*      csr_src = (int*)carve((size_t)N_EDGES * 4);
    int*      csr_dst = (int*)carve((size_t)N_EDGES * 4);
    float2*   fac0    = (float2*)carve((size_t)N_EDGES * 8);
    float2*   fac1    = (float2*)carve((size_t)N_EDGES * 8);
    float*    h2f     = (float*)carve((size_t)N_NODES * 64 * 4);
    uint16_t* h2b     = (uint16_t*)carve((size_t)N_NODES * 64 * 2);
    float*    proj    = (float*)carve(N_NODES * 4 * 4);
    uint32_t* fc      = (uint32_t*)carve((size_t)N_NODES * 64 * 4);
    float4*   p1b     = (float4*)carve((size_t)N_NODES * 16);

    hipMemsetAsync(cnt, 0, N_NODES * 4, stream);
    k_count<<<(N_EDGES + 255) / 256, 256, 0, stream>>>(dst, cnt);
    k_block_sums<<<98, 256, 0, stream>>>(cnt, bsum);
    k_scan_mid<<<1, 128, 0, stream>>>(bsum, ex, rowptr, 98);
    k_scan_final<<<98, 256, 0, stream>>>(cnt, ex, rowptr, cursor, dinv);
    k_prep<<<(KPAD * OUTC + 255) / 256, 256, 0, stream>>>(Wl, bl, glw, glb, W1, Wp, consts);
    k_gemm_front<<<(N_NODES + 127) / 128, 256, 0, stream>>>(x, Wp, consts, b1, h2f, h2b, proj);
    k_scatter_fac<<<(N_EDGES + 255) / 256, 256, 0, stream>>>(src, dst, cursor, dinv,
                                                             (const float4*)proj, csr_src, csr_dst, fac0);
    k_hop0<<<N_NODES / 4, 256, 0, stream>>>(rowptr, csr_src, fac0, h2b, h2f, faw, fab, fc, p1b);
    k_fac1<<<(N_EDGES + 255) / 256, 256, 0, stream>>>(csr_src, csr_dst, dinv, p1b, fac1);
    k_hop1<<<N_NODES / 4, 256, 0, stream>>>(rowptr, csr_src, fac1, fc, h2f, W2, b2, out);
}

// Round 4
// 491.736 us; speedup vs baseline: 1.7915x; 1.1213x over previous
//
#include <hip/hip_runtime.h>
#include <hip/hip_bf16.h>
#include <stdint.h>

constexpr int N_NODES = 50000;
constexpr int N_EDGES = 1600000;
constexpr int IN_DIM  = 500;
constexpr int KPAD    = 512;   // zero-padded K for clean tiling
constexpr int HID     = 64;
constexpr int OUTC    = 68;    // 64 h2 cols + 4 composed projection cols

#define DEVI __device__ __forceinline__

DEVI float wred64(float v) {
#pragma unroll
    for (int m = 32; m; m >>= 1) v += __shfl_xor(v, m, 64);
    return v;
}

DEVI float bf_hi(uint32_t u) { return __uint_as_float(u & 0xffff0000u); }
DEVI float bf_lo(uint32_t u) { return __uint_as_float(u << 16); }

DEVI uint16_t f2bf(float f) {
    union { __hip_bfloat16 h; uint16_t u; } c;
    c.h = __float2bfloat16(f);
    return c.u;
}

// ---------------- CSR build ----------------
__global__ void k_count(const int* __restrict__ dst, int* __restrict__ cnt) {
    int e = blockIdx.x * 256 + threadIdx.x;
    if (e < N_EDGES) atomicAdd(&cnt[dst[e]], 1);
}

__global__ void k_block_sums(const int* __restrict__ cnt, int* __restrict__ bsum) {
    __shared__ int red[256];
    int t = threadIdx.x;
    int i0 = blockIdx.x * 512 + t;
    int a = (i0 < N_NODES) ? cnt[i0] : 0;
    int b = (i0 + 256 < N_NODES) ? cnt[i0 + 256] : 0;
    red[t] = a + b;
    __syncthreads();
    for (int s = 128; s > 0; s >>= 1) {
        if (t < s) red[t] += red[t + s];
        __syncthreads();
    }
    if (t == 0) bsum[blockIdx.x] = red[0];
}

__global__ void k_scan_mid(const int* __restrict__ bsum, int* __restrict__ ex,
                           int* __restrict__ rowptr, int nb) {
    __shared__ int lds[128];
    int t = threadIdx.x;
    int v = (t < nb) ? bsum[t] : 0;
    lds[t] = v;
    __syncthreads();
    for (int d = 1; d < 128; d <<= 1) {
        int w = (t >= d) ? lds[t - d] : 0;
        __syncthreads();
        lds[t] += w;
        __syncthreads();
    }
    if (t < nb) ex[t] = lds[t] - v;
    if (t == 127) rowptr[N_NODES] = lds[127];
}

__global__ void k_scan_final(const int* __restrict__ cnt, const int* __restrict__ ex,
                             int* __restrict__ rowptr, int* __restrict__ cursor,
                             float* __restrict__ dinv) {
    __shared__ int lds[256];
    int t = threadIdx.x;
    int i0 = blockIdx.x * 512 + 2 * t;
    int i1 = i0 + 1;
    int a0 = (i0 < N_NODES) ? cnt[i0] : 0;
    int a1 = (i1 < N_NODES) ? cnt[i1] : 0;
    int s = a0 + a1;
    lds[t] = s;
    __syncthreads();
    for (int d = 1; d < 256; d <<= 1) {
        int w = (t >= d) ? lds[t - d] : 0;
        __syncthreads();
        lds[t] += w;
        __syncthreads();
    }
    int base = ex[blockIdx.x] + lds[t] - s;  // exclusive offset of this pair
    if (i0 < N_NODES) {
        rowptr[i0] = base; cursor[i0] = base;
        dinv[i0] = rsqrtf((float)(a0 > 1 ? a0 : 1));
    }
    if (i1 < N_NODES) {
        rowptr[i1] = base + a0; cursor[i1] = base + a0;
        dinv[i1] = rsqrtf((float)(a1 > 1 ? a1 : 1));
    }
}

// scatter + hop-0 edge factors (edge-parallel tanh; needs proj ready)
__global__ void k_scatter_fac(const int* __restrict__ src, const int* __restrict__ dst,
                              int* __restrict__ cursor, const float* __restrict__ dinv,
                              const float4* __restrict__ projv,
                              int* __restrict__ csr_src, int* __restrict__ csr_dst,
                              float2* __restrict__ fac0) {
    int e = blockIdx.x * 256 + threadIdx.x;
    if (e >= N_EDGES) return;
    int u = src[e], v = dst[e];
    int pos = atomicAdd(&cursor[v], 1);
    csr_src[pos] = u;
    csr_dst[pos] = v;
    float dd = dinv[v] * dinv[u];
    float4 pv = projv[v], pu = projv[u];
    fac0[pos] = make_float2(tanhf(pv.x + pu.y) * dd, tanhf(pv.z + pu.w) * dd);
}

// hop-1 edge factors from p1 (pos-parallel)
__global__ void k_fac1(const int* __restrict__ csr_src, const int* __restrict__ csr_dst,
                       const float* __restrict__ dinv, const float4* __restrict__ p1,
                       float2* __restrict__ fac1) {
    int pos = blockIdx.x * 256 + threadIdx.x;
    if (pos >= N_EDGES) return;
    int u = csr_src[pos], v = csr_dst[pos];
    float dd = dinv[v] * dinv[u];
    float4 pv = p1[v], pu = p1[u];
    fac1[pos] = make_float2(tanhf(pv.x + pu.y) * dd, tanhf(pv.z + pu.w) * dd);
}

// ---- weight prep: Wp[512][68] = [W1 | Wl@glw_pd0 | Wl@glw_ps0 | Wl@glw_pd1 | Wl@glw_ps1], 0 for k>=500 ----
__global__ void k_prep(const float* __restrict__ Wl, const float* __restrict__ bl,
                       const float* __restrict__ glw, const float* __restrict__ glb,
                       const float* __restrict__ W1,
                       float* __restrict__ Wp, float* __restrict__ consts) {
    int idx = blockIdx.x * 256 + threadIdx.x;
    if (idx < KPAD * OUTC) {
        int k = idx / OUTC, c = idx - k * OUTC;
        float v = 0.f;
        if (k < IN_DIM) {
            if (c < HID) {
                v = W1[k * HID + c];
            } else {
                int pp = c - HID, g = pp >> 1, half = pp & 1;
                const float* wv = glw + g * 128 + half * 64;
                float s = 0.f;
                for (int j = 0; j < 64; ++j) s += Wl[k * 64 + j] * wv[j];
                v = s;
            }
        }
        Wp[idx] = v;
    }
    if (idx < 4) {
        int g = idx >> 1, half = idx & 1;
        const float* wv = glw + g * 128 + half * 64;
        float s = 0.f;
        for (int j = 0; j < 64; ++j) s += bl[j] * wv[j];
        if (half) s += glb[g];
        consts[idx] = s;
    }
}

// ---------------- fused front GEMM: h2 = relu(x@W1+b1), proj = x@(composed) + consts ----
// BM=64, BK=64, 256 threads (782 blocks -> ~12 waves/CU). Thread tile = 1 row x 17 cols.
// xT[64][65]: both staging writes and compute reads are 2-way bank aliased (free).
// Weights via wave-uniform scalar loads (constant cache, no vector-mem traffic).
__global__ __launch_bounds__(256)
void k_gemm_front(const float* __restrict__ x, const float* __restrict__ Wp,
                  const float* __restrict__ consts, const float* __restrict__ b1,
                  float* __restrict__ h2f, uint16_t* __restrict__ h2b,
                  float* __restrict__ proj) {
    __shared__ float xT[64][65];   // [k][row]
    int tid   = threadIdx.x;
    int cg    = __builtin_amdgcn_readfirstlane(tid >> 6);  // wave-uniform col group 0..3
    int lane  = tid & 63;
    int c0    = cg * 17;
    int rbase = blockIdx.x * 64;

    int srow  = tid >> 2;          // staging row 0..63
    int skb   = (tid & 3) * 16;    // staging k base: 16 floats = 4x float4
    int sgrow = rbase + srow;
    const float* xr = x + (size_t)sgrow * IN_DIM;

    float acc[17];
#pragma unroll
    for (int i = 0; i < 17; ++i) acc[i] = 0.f;

    for (int kt = 0; kt < 8; ++kt) {
        int k0 = kt * 64;
        // ---- stage x[rbase..rbase+63][k0..k0+63] transposed ----
#pragma unroll
        for (int it = 0; it < 4; ++it) {
            int kloc = skb + it * 4;
            int gk   = k0 + kloc;
            float4 v = make_float4(0.f, 0.f, 0.f, 0.f);
            if (sgrow < N_NODES) {
                if (gk + 3 < IN_DIM) {
                    v = *(const float4*)(xr + gk);
                } else {
                    if (gk + 0 < IN_DIM) v.x = xr[gk + 0];
                    if (gk + 1 < IN_DIM) v.y = xr[gk + 1];
                    if (gk + 2 < IN_DIM) v.z = xr[gk + 2];
                    if (gk + 3 < IN_DIM) v.w = xr[gk + 3];
                }
            }
            xT[kloc + 0][srow] = v.x;
            xT[kloc + 1][srow] = v.y;
            xT[kloc + 2][srow] = v.z;
            xT[kloc + 3][srow] = v.w;
        }
        __syncthreads();

        // ---- compute: 1 ds_read + 17 wave-uniform-weight FMAs per k ----
        const float* wbase = Wp + k0 * OUTC + c0;
#pragma unroll 4
        for (int k = 0; k < 64; ++k) {
            float xv = xT[k][lane];
            const float* wk = wbase + k * OUTC;
#pragma unroll
            for (int i = 0; i < 17; ++i) acc[i] = fmaf(xv, wk[i], acc[i]);
        }
        __syncthreads();
    }

    // ---- epilogue ----
    int grow = rbase + lane;
    if (grow < N_NODES) {
#pragma unroll
        for (int i = 0; i < 17; ++i) {
            int c = c0 + i;
            float v = acc[i];
            if (c < HID) {
                float hv = fmaxf(v + b1[c], 0.f);
                h2f[(size_t)grow * HID + c] = hv;
                h2b[(size_t)grow * HID + c] = f2bf(hv);
            } else {
                proj[grow * 4 + (c - HID)] = v + consts[c - HID];
            }
        }
    }
}

// ---------------- hop 0 (both graphs fused), feat=h2 (bf16 gather); writes interleaved bf16 featcat + p1 ----
__global__ __launch_bounds__(256)
void k_hop0(const int* __restrict__ rowptr, const int* __restrict__ csr_src,
            const float2* __restrict__ fac0, const uint16_t* __restrict__ h2b,
            const float* __restrict__ h2f, const float* __restrict__ faw,
            const float* __restrict__ fab,
            uint32_t* __restrict__ fc, float4* __restrict__ p1) {
    int wave = __builtin_amdgcn_readfirstlane(threadIdx.x >> 6);
    int lane = threadIdx.x & 63;
    int v = blockIdx.x * 4 + wave;
    int s = __builtin_amdgcn_readfirstlane(rowptr[v]);
    int e = __builtin_amdgcn_readfirstlane(rowptr[v + 1]);
    float acc0 = 0.f, acc1 = 0.f;
    for (int b2 = s; b2 < e; b2 += 64) {
        int pos = b2 + lane;
        bool val = pos < e;
        int idx = val ? csr_src[pos] : 0;
        float2 f = val ? fac0[pos] : make_float2(0.f, 0.f);
        int cnt = min(64, e - b2);
        for (int j = 0; j < cnt; ++j) {
            int u = __shfl(idx, j, 64);
            float t0 = __shfl(f.x, j, 64);
            float t1 = __shfl(f.y, j, 64);
            float hv = bf_lo((uint32_t)h2b[(size_t)u * 64 + lane]);
            acc0 = fmaf(t0, hv, acc0);
            acc1 = fmaf(t1, hv, acc1);
        }
    }
    float h2v = h2f[(size_t)v * 64 + lane];
    float f0 = fmaf(0.7f, acc0, 0.3f * h2v);
    float f1 = fmaf(0.7f, acc1, 0.3f * h2v);
    fc[(size_t)v * 64 + lane] = (uint32_t)f2bf(f0) | ((uint32_t)f2bf(f1) << 16);
    // hop-1 gate projections
    float wpd0 = faw[1 * 128 + lane];
    float wps0 = faw[1 * 128 + 64 + lane];
    float wpd1 = faw[3 * 128 + lane];
    float wps1 = faw[3 * 128 + 64 + lane];
    float r0 = wred64(f0 * wpd0);
    float r1 = wred64(f0 * wps0);
    float r2 = wred64(f1 * wpd1);
    float r3 = wred64(f1 * wps1);
    if (lane == 0) p1[v] = make_float4(r0, r1 + fab[1], r2, r3 + fab[3]);
}

// ---------------- hop 1 (both graphs fused) + final output GEMM [128]->7 ----
__global__ __launch_bounds__(256)
void k_hop1(const int* __restrict__ rowptr, const int* __restrict__ csr_src,
            const float2* __restrict__ fac1, const uint32_t* __restrict__ fc,
            const float* __restrict__ h2f, const float* __restrict__ W2,
            const float* __restrict__ b2, float* __restrict__ out) {
    int wave = __builtin_amdgcn_readfirstlane(threadIdx.x >> 6);
    int lane = threadIdx.x & 63;
    int v = blockIdx.x * 4 + wave;
    int s = __builtin_amdgcn_readfirstlane(rowptr[v]);
    int e = __builtin_amdgcn_readfirstlane(rowptr[v + 1]);
    float acc0 = 0.f, acc1 = 0.f;
    for (int b2 = s; b2 < e; b2 += 64) {
        int pos = b2 + lane;
        bool val = pos < e;
        int idx = val ? csr_src[pos] : 0;
        float2 f = val ? fac1[pos] : make_float2(0.f, 0.f);
        int cnt = min(64, e - b2);
        for (int j = 0; j < cnt; ++j) {
            int u = __shfl(idx, j, 64);
            float t0 = __shfl(f.x, j, 64);
            float t1 = __shfl(f.y, j, 64);
            uint32_t pk = fc[(size_t)u * 64 + lane];
            acc0 = fmaf(t0, bf_lo(pk & 0xffffu), acc0);
            acc1 = fmaf(t1, bf_hi(pk), acc1);
        }
    }
    float h2v = h2f[(size_t)v * 64 + lane];
    float f0 = fmaf(0.7f, acc0, 0.3f * h2v);
    float f1 = fmaf(0.7f, acc1, 0.3f * h2v);
#pragma unroll
    for (int o = 0; o < 7; ++o) {
        float contrib = f0 * W2[lane * 7 + o] + f1 * W2[(64 + lane) * 7 + o];
        float sum = wred64(contrib);
        if (lane == 0) out[v * 7 + o] = sum + b2[o];
    }
}

extern "C" void kernel_launch(void* const* d_in, const int* in_sizes, int n_in,
                              void* d_out, int out_size, void* d_ws, size_t ws_size,
                              hipStream_t stream) {
    const float* x   = (const float*)d_in[0];
    const int*   src = (const int*)d_in[1];
    const int*   dst = (const int*)d_in[2];
    const float* Wl  = (const float*)d_in[3];
    const float* bl  = (const float*)d_in[4];
    const float* glw = (const float*)d_in[5];
    const float* glb = (const float*)d_in[6];
    const float* W1  = (const float*)d_in[7];
    const float* b1  = (const float*)d_in[8];
    const float* faw = (const float*)d_in[9];
    const float* fab = (const float*)d_in[10];
    const float* W2  = (const float*)d_in[11];
    const float* b2  = (const float*)d_in[12];
    float* out = (float*)d_out;

    uint8_t* p = (uint8_t*)d_ws;
    auto carve = [&](size_t bytes) {
        uint8_t* q = p;
        p += (bytes + 255) & ~(size_t)255;
        return q;
    };
    float*    Wp      = (float*)carve((size_t)KPAD * OUTC * 4);
    float*    consts  = (float*)carve(16);
    int*      cnt     = (int*)carve(N_NODES * 4);
    int*      rowptr  = (int*)carve((N_NODES + 1) * 4);
    int*      cursor  = (int*)carve(N_NODES * 4);
    float*    dinv    = (float*)carve(N_NODES * 4);
    int*      bsum    = (int*)carve(98 * 4);
    int*      ex      = (int*)carve(98 * 4);
    int*      csr_src = (int*)carve((size_t)N_EDGES * 4);
    int*      csr_dst = (int*)carve((size_t)N_EDGES * 4);
    float2*   fac0    = (float2*)carve((size_t)N_EDGES * 8);
    float2*   fac1    = (float2*)carve((size_t)N_EDGES * 8);
    float*    h2f     = (float*)carve((size_t)N_NODES * 64 * 4);
    uint16_t* h2b     = (uint16_t*)carve((size_t)N_NODES * 64 * 2);
    float*    proj    = (float*)carve(N_NODES * 4 * 4);
    uint32_t* fc      = (uint32_t*)carve((size_t)N_NODES * 64 * 4);
    float4*   p1b     = (float4*)carve((size_t)N_NODES * 16);

    hipMemsetAsync(cnt, 0, N_NODES * 4, stream);
    k_count<<<(N_EDGES + 255) / 256, 256, 0, stream>>>(dst, cnt);
    k_block_sums<<<98, 256, 0, stream>>>(cnt, bsum);
    k_scan_mid<<<1, 128, 0, stream>>>(bsum, ex, rowptr, 98);
    k_scan_final<<<98, 256, 0, stream>>>(cnt, ex, rowptr, cursor, dinv);
    k_prep<<<(KPAD * OUTC + 255) / 256, 256, 0, stream>>>(Wl, bl, glw, glb, W1, Wp, consts);
    k_gemm_front<<<(N_NODES + 63) / 64, 256, 0, stream>>>(x, Wp, consts, b1, h2f, h2b, proj);
    k_scatter_fac<<<(N_EDGES + 255) / 256, 256, 0, stream>>>(src, dst, cursor, dinv,
                                                             (const float4*)proj, csr_src, csr_dst, fac0);
    k_hop0<<<N_NODES / 4, 256, 0, stream>>>(rowptr, csr_src, fac0, h2b, h2f, faw, fab, fc, p1b);
    k_fac1<<<(N_EDGES + 255) / 256, 256, 0, stream>>>(csr_src, csr_dst, dinv, p1b, fac1);
    k_hop1<<<N_NODES / 4, 256, 0, stream>>>(rowptr, csr_src, fac1, fc, h2f, W2, b2, out);
}